// Round 7
// baseline (563.605 us; speedup 1.0000x reference)
//
#include <hip/hip_runtime.h>

#define NN 10000
#define NE 320000
#define F  128
#define BLK 256

// ---------- CSR build ----------
__global__ void zero_deg(int* __restrict__ deg) {
    int i = blockIdx.x * 256 + threadIdx.x;
    if (i < NN) deg[i] = 0;
}

__global__ void count_kernel(const int* __restrict__ dst, int* __restrict__ deg) {
    int e = blockIdx.x * 256 + threadIdx.x;
    if (e < NE) atomicAdd(&deg[dst[e]], 1);
}

__global__ __launch_bounds__(1024) void scan_kernel(const int* __restrict__ deg,
                                                    int* __restrict__ offs,
                                                    int* __restrict__ cursor,
                                                    float* __restrict__ invdeg) {
    __shared__ int s[1024];
    int t = threadIdx.x;
    int lo = t * 10;
    int hi = min(lo + 10, NN);
    int sum = 0;
    for (int i = lo; i < hi; ++i) sum += deg[i];
    s[t] = sum;
    __syncthreads();
    for (int off = 1; off < 1024; off <<= 1) {
        int v = (t >= off) ? s[t - off] : 0;
        __syncthreads();
        s[t] += v;
        __syncthreads();
    }
    int base = s[t] - sum;  // exclusive prefix
    for (int i = lo; i < hi; ++i) {
        int c = deg[i];
        offs[i]   = base;
        cursor[i] = base;
        invdeg[i] = 1.0f / (float)c;  // every node has >=1 in-edge
        base += c;
    }
    if (t == 0) offs[NN] = NE;
}

// fill CSR; also pre-resolve csrc[p] = src[e]
__global__ void fill_kernel(const int* __restrict__ dst, const int* __restrict__ src,
                            int* __restrict__ cursor, int* __restrict__ csr,
                            int* __restrict__ csrc) {
    int e = blockIdx.x * 256 + threadIdx.x;
    if (e < NE) {
        int p = atomicAdd(&cursor[dst[e]], 1);
        csr[p] = e;
        csrc[p] = src[e];
    }
}

// ---------- gather (mean / fused-relu-edge variants) ----------
// Out[n] = invdeg[n] * sum_{i in seg(n)} op(T[idx[i]])
//   MODE 0: op(v) = v                                  (layer-1 seg-mean of edge_feats)
//   MODE 1: op(v) = relu(0.5*(v + T[n]) + bias)        (fused prev-layer edge compute)
// block = 256 threads = 2 nodes x 4 edge-slots x 32 float4 chunks; 4 rows in flight/thread
template <int MODE>
__global__ __launch_bounds__(256) void gather_k(const float4* __restrict__ T,
                                                const int* __restrict__ idx,
                                                const int* __restrict__ offs,
                                                const float4* __restrict__ bias4,
                                                const float* __restrict__ invdeg,
                                                float4* __restrict__ Out) {
    __shared__ float4 red[8][32];
    int t  = threadIdx.x;
    int ns = t >> 7;          // node slot 0..1
    int es = (t >> 5) & 3;    // edge slot 0..3
    int ch = t & 31;          // float4 chunk 0..31
    int n  = blockIdx.x * 2 + ns;
    int a = offs[n], bnd = offs[n + 1];

    float4 zn = make_float4(0.f, 0.f, 0.f, 0.f);
    float4 bb = make_float4(0.f, 0.f, 0.f, 0.f);
    if (MODE == 1) { zn = T[(size_t)n * 32 + ch]; bb = bias4[ch]; }
    float ax = 0.f, ay = 0.f, az = 0.f, aw = 0.f;

    int i = a + es;
    for (; i + 12 < bnd; i += 16) {       // 4 rows in flight per thread
        int s0 = idx[i], s1 = idx[i + 4], s2 = idx[i + 8], s3 = idx[i + 12];
        float4 v0 = T[(size_t)s0 * 32 + ch];
        float4 v1 = T[(size_t)s1 * 32 + ch];
        float4 v2 = T[(size_t)s2 * 32 + ch];
        float4 v3 = T[(size_t)s3 * 32 + ch];
        if (MODE == 1) {
            ax += fmaxf(0.5f * (v0.x + zn.x) + bb.x, 0.f) + fmaxf(0.5f * (v1.x + zn.x) + bb.x, 0.f)
                + fmaxf(0.5f * (v2.x + zn.x) + bb.x, 0.f) + fmaxf(0.5f * (v3.x + zn.x) + bb.x, 0.f);
            ay += fmaxf(0.5f * (v0.y + zn.y) + bb.y, 0.f) + fmaxf(0.5f * (v1.y + zn.y) + bb.y, 0.f)
                + fmaxf(0.5f * (v2.y + zn.y) + bb.y, 0.f) + fmaxf(0.5f * (v3.y + zn.y) + bb.y, 0.f);
            az += fmaxf(0.5f * (v0.z + zn.z) + bb.z, 0.f) + fmaxf(0.5f * (v1.z + zn.z) + bb.z, 0.f)
                + fmaxf(0.5f * (v2.z + zn.z) + bb.z, 0.f) + fmaxf(0.5f * (v3.z + zn.z) + bb.z, 0.f);
            aw += fmaxf(0.5f * (v0.w + zn.w) + bb.w, 0.f) + fmaxf(0.5f * (v1.w + zn.w) + bb.w, 0.f)
                + fmaxf(0.5f * (v2.w + zn.w) + bb.w, 0.f) + fmaxf(0.5f * (v3.w + zn.w) + bb.w, 0.f);
        } else {
            ax += v0.x + v1.x + v2.x + v3.x;
            ay += v0.y + v1.y + v2.y + v3.y;
            az += v0.z + v1.z + v2.z + v3.z;
            aw += v0.w + v1.w + v2.w + v3.w;
        }
    }
    for (; i < bnd; i += 4) {
        int s0 = idx[i];
        float4 v0 = T[(size_t)s0 * 32 + ch];
        if (MODE == 1) {
            ax += fmaxf(0.5f * (v0.x + zn.x) + bb.x, 0.f);
            ay += fmaxf(0.5f * (v0.y + zn.y) + bb.y, 0.f);
            az += fmaxf(0.5f * (v0.z + zn.z) + bb.z, 0.f);
            aw += fmaxf(0.5f * (v0.w + zn.w) + bb.w, 0.f);
        } else {
            ax += v0.x; ay += v0.y; az += v0.z; aw += v0.w;
        }
    }

    red[t >> 5][ch] = make_float4(ax, ay, az, aw);
    __syncthreads();
    if (t < 64) {
        int ns2 = t >> 5, c2 = t & 31;
        float4 r0 = red[ns2 * 4 + 0][c2];
        float4 r1 = red[ns2 * 4 + 1][c2];
        float4 r2 = red[ns2 * 4 + 2][c2];
        float4 r3 = red[ns2 * 4 + 3][c2];
        int n2 = blockIdx.x * 2 + ns2;
        float sc = invdeg[n2];
        float4 r;
        r.x = (r0.x + r1.x + r2.x + r3.x) * sc;
        r.y = (r0.y + r1.y + r2.y + r3.y) * sc;
        r.z = (r0.z + r1.z + r2.z + r3.z) * sc;
        r.w = (r0.w + r1.w + r2.w + r3.w) * sc;
        Out[(size_t)n2 * 32 + c2] = r;
    }
}

// ---------- fused sum-gather + per-node matvec ----------
// x[n] = sum_{i in seg(n)} T[idx[i]]   (2 nodes per block, reduced into LDS)
// Z[n] = W @ x[n]                      (both thread-halves: one node each)
template <int OUT>
__global__ __launch_bounds__(256) void sum_gemm_k(const float4* __restrict__ T,
                                                  const int* __restrict__ idx,
                                                  const int* __restrict__ offs,
                                                  const float* __restrict__ Wm,
                                                  float* __restrict__ Z) {
    __shared__ float4 red[8][32];
    __shared__ float  xs[2][128];
    int t  = threadIdx.x;
    int ns = t >> 7;
    int es = (t >> 5) & 3;
    int ch = t & 31;
    int n  = blockIdx.x * 2 + ns;
    int a = offs[n], bnd = offs[n + 1];

    float ax = 0.f, ay = 0.f, az = 0.f, aw = 0.f;
    int i = a + es;
    for (; i + 12 < bnd; i += 16) {
        int s0 = idx[i], s1 = idx[i + 4], s2 = idx[i + 8], s3 = idx[i + 12];
        float4 v0 = T[(size_t)s0 * 32 + ch];
        float4 v1 = T[(size_t)s1 * 32 + ch];
        float4 v2 = T[(size_t)s2 * 32 + ch];
        float4 v3 = T[(size_t)s3 * 32 + ch];
        ax += v0.x + v1.x + v2.x + v3.x;
        ay += v0.y + v1.y + v2.y + v3.y;
        az += v0.z + v1.z + v2.z + v3.z;
        aw += v0.w + v1.w + v2.w + v3.w;
    }
    for (; i < bnd; i += 4) {
        int s0 = idx[i];
        float4 v0 = T[(size_t)s0 * 32 + ch];
        ax += v0.x; ay += v0.y; az += v0.z; aw += v0.w;
    }

    red[t >> 5][ch] = make_float4(ax, ay, az, aw);
    __syncthreads();
    if (t < 64) {
        int ns2 = t >> 5, c2 = t & 31;
        float4 r0 = red[ns2 * 4 + 0][c2];
        float4 r1 = red[ns2 * 4 + 1][c2];
        float4 r2 = red[ns2 * 4 + 2][c2];
        float4 r3 = red[ns2 * 4 + 3][c2];
        float4 r;
        r.x = r0.x + r1.x + r2.x + r3.x;
        r.y = r0.y + r1.y + r2.y + r3.y;
        r.z = r0.z + r1.z + r2.z + r3.z;
        r.w = r0.w + r1.w + r2.w + r3.w;
        *reinterpret_cast<float4*>(&xs[ns2][c2 * 4]) = r;
    }
    __syncthreads();

    // matvec: thread-half ns computes node ns; lane o = t & 127 its output row
    if (OUT == 128 || (t & 127) < OUT) {
        int o = t & 127;
        const float4* wrow = reinterpret_cast<const float4*>(&Wm[(size_t)o * 128]);
        const float* xv = xs[ns];
        float acc = 0.f;
#pragma unroll 8
        for (int k4 = 0; k4 < 32; ++k4) {
            float4 w  = wrow[k4];
            float4 x0 = *reinterpret_cast<const float4*>(&xv[k4 * 4]);
            acc += w.x * x0.x + w.y * x0.y + w.z * x0.z + w.w * x0.w;
        }
        Z[(size_t)n * OUT + o] = acc;
    }
}

// ---------- final edge output: out[e] = 0.5*(z5[src]+z5[dst]) + b5 (64 feats) ----------
__global__ __launch_bounds__(256) void edge_out(const float4* __restrict__ z5,
                                                const float4* __restrict__ b5v,
                                                const int* __restrict__ src,
                                                const int* __restrict__ dst,
                                                float4* __restrict__ outp) {
    int t = blockIdx.x * 256 + threadIdx.x;
    int e = t >> 4, ch = t & 15;
    if (e < NE) {
        float4 a = z5[(size_t)src[e] * 16 + ch];
        float4 b = z5[(size_t)dst[e] * 16 + ch];
        float4 c = b5v[ch];
        float4 r;
        r.x = 0.5f * (a.x + b.x) + c.x;
        r.y = 0.5f * (a.y + b.y) + c.y;
        r.z = 0.5f * (a.z + b.z) + c.z;
        r.w = 0.5f * (a.w + b.w) + c.w;
        outp[(size_t)e * 16 + ch] = r;
    }
}

extern "C" void kernel_launch(void* const* d_in, const int* in_sizes, int n_in,
                              void* d_out, int out_size, void* d_ws, size_t ws_size,
                              hipStream_t stream) {
    const float* ef  = (const float*)d_in[0];
    const int*   src = (const int*)d_in[1];
    const int*   dst = (const int*)d_in[2];
    const float* W1 = (const float*)d_in[3];  const float* b1 = (const float*)d_in[4];
    const float* W2 = (const float*)d_in[5];  const float* b2 = (const float*)d_in[6];
    const float* W3 = (const float*)d_in[7];  const float* b3 = (const float*)d_in[8];
    const float* W4 = (const float*)d_in[9];  const float* b4 = (const float*)d_in[10];
    const float* W5 = (const float*)d_in[11]; const float* b5 = (const float*)d_in[12];
    float* out = (float*)d_out;

    char* p = (char*)d_ws;
    auto alloc = [&](size_t bytes) {
        char* r = p;
        p += (bytes + 255) & ~(size_t)255;
        return r;
    };
    int*   deg    = (int*)alloc(NN * 4);
    int*   offs   = (int*)alloc((NN + 1) * 4);
    int*   cursor = (int*)alloc(NN * 4);
    int*   csr    = (int*)alloc((size_t)NE * 4);
    int*   csrc   = (int*)alloc((size_t)NE * 4);
    float* invdeg = (float*)alloc(NN * 4);
    float* nodeA  = (float*)alloc((size_t)NN * F * 4);
    float* z      = (float*)alloc((size_t)NN * F * 4);

    // CSR build (4 dispatches, no rocclr fill nodes in the graph)
    zero_deg<<<(NN + 255) / 256, 256, 0, stream>>>(deg);
    count_kernel<<<(NE + 255) / 256, 256, 0, stream>>>(dst, deg);
    scan_kernel<<<1, 1024, 0, stream>>>(deg, offs, cursor, invdeg);
    fill_kernel<<<(NE + 255) / 256, 256, 0, stream>>>(dst, src, cursor, csr, csrc);

    const int GG = NN / 2;                 // 5000 blocks, 2 nodes each
    const float4* z4 = (const float4*)z;
    float4* nodeA4 = (float4*)nodeA;

    // ---- layer 1 ----
    gather_k<0><<<GG, BLK, 0, stream>>>((const float4*)ef, csr, offs, nullptr, invdeg, nodeA4);
    sum_gemm_k<128><<<GG, BLK, 0, stream>>>((const float4*)nodeA, csrc, offs, W1, z);

    // ---- layers 2..4 (prev layer's edge compute fused into the relu gather) ----
    const float* Wl[3] = {W2, W3, W4};
    const float* bl[3] = {b1, b2, b3};
    for (int L = 0; L < 3; ++L) {
        gather_k<1><<<GG, BLK, 0, stream>>>(z4, csrc, offs, (const float4*)bl[L], invdeg, nodeA4);
        sum_gemm_k<128><<<GG, BLK, 0, stream>>>((const float4*)nodeA, csrc, offs, Wl[L], z);
    }

    // ---- layer 5 ----
    gather_k<1><<<GG, BLK, 0, stream>>>(z4, csrc, offs, (const float4*)b4, invdeg, nodeA4);
    sum_gemm_k<64><<<GG, BLK, 0, stream>>>((const float4*)nodeA, csrc, offs, W5, z);

    // ---- final per-edge output (82 MB write) ----
    edge_out<<<(NE * 16 + 255) / 256, BLK, 0, stream>>>(z4, (const float4*)b5, src, dst, (float4*)out);
}

// Round 8
// 386.036 us; speedup vs baseline: 1.4600x; 1.4600x over previous
//
#include <hip/hip_runtime.h>

#define NN 10000
#define NE 320000
#define F  128
#define BLK 256

// ---------- bf16 helpers (storage-only; all accumulation fp32) ----------
__device__ __forceinline__ float bf2f(unsigned v16) {
    return __uint_as_float(v16 << 16);
}
__device__ __forceinline__ unsigned f2bf(float f) {           // round-to-nearest-even
    unsigned u = __float_as_uint(f);
    return (u + 0x7FFFu + ((u >> 16) & 1u)) >> 16;
}
__device__ __forceinline__ unsigned pack2(float lo, float hi) {
    return f2bf(lo) | (f2bf(hi) << 16);
}
__device__ __forceinline__ void unpack8(uint4 q, float* v) {
    v[0] = bf2f(q.x & 0xffffu); v[1] = bf2f(q.x >> 16);
    v[2] = bf2f(q.y & 0xffffu); v[3] = bf2f(q.y >> 16);
    v[4] = bf2f(q.z & 0xffffu); v[5] = bf2f(q.z >> 16);
    v[6] = bf2f(q.w & 0xffffu); v[7] = bf2f(q.w >> 16);
}

// ---------- CSR build (round-6 proven) ----------
__global__ void count_kernel(const int* __restrict__ dst, int* __restrict__ deg) {
    int e = blockIdx.x * 256 + threadIdx.x;
    if (e < NE) atomicAdd(&deg[dst[e]], 1);
}

__global__ __launch_bounds__(1024) void scan_kernel(const int* __restrict__ deg,
                                                    int* __restrict__ offs,
                                                    int* __restrict__ cursor,
                                                    float* __restrict__ invdeg) {
    __shared__ int s[1024];
    int t = threadIdx.x;
    int lo = t * 10;
    int hi = min(lo + 10, NN);
    int sum = 0;
    for (int i = lo; i < hi; ++i) sum += deg[i];
    s[t] = sum;
    __syncthreads();
    for (int off = 1; off < 1024; off <<= 1) {
        int v = (t >= off) ? s[t - off] : 0;
        __syncthreads();
        s[t] += v;
        __syncthreads();
    }
    int base = s[t] - sum;  // exclusive prefix
    for (int i = lo; i < hi; ++i) {
        int c = deg[i];
        offs[i]   = base;
        cursor[i] = base;
        invdeg[i] = 1.0f / (float)c;
        base += c;
    }
    if (t == 0) offs[NN] = NE;
}

__global__ void fill_kernel(const int* __restrict__ dst, const int* __restrict__ src,
                            int* __restrict__ cursor, int* __restrict__ csr,
                            int* __restrict__ csrc) {
    int e = blockIdx.x * 256 + threadIdx.x;
    if (e < NE) {
        int p = atomicAdd(&cursor[dst[e]], 1);
        csr[p] = e;
        csrc[p] = src[e];
    }
}

// ---------- layer-1 seg-mean: fp32 edge_feats -> bf16 nodeA ----------
// 2 nodes x 4 edge-slots x 32 float4-chunks; 4 rows in flight per thread
__global__ __launch_bounds__(256) void seg_mean_k(const float4* __restrict__ ef,
                                                  const int* __restrict__ idx,
                                                  const int* __restrict__ offs,
                                                  const float* __restrict__ invdeg,
                                                  ushort4* __restrict__ Out) {
    __shared__ float4 red[8][32];
    int t  = threadIdx.x;
    int ns = t >> 7, es = (t >> 5) & 3, ch = t & 31;
    int n  = blockIdx.x * 2 + ns;
    int a = offs[n], bnd = offs[n + 1];

    float ax = 0.f, ay = 0.f, az = 0.f, aw = 0.f;
    int i = a + es;
    for (; i + 12 < bnd; i += 16) {
        int s0 = idx[i], s1 = idx[i + 4], s2 = idx[i + 8], s3 = idx[i + 12];
        float4 v0 = ef[(size_t)s0 * 32 + ch];
        float4 v1 = ef[(size_t)s1 * 32 + ch];
        float4 v2 = ef[(size_t)s2 * 32 + ch];
        float4 v3 = ef[(size_t)s3 * 32 + ch];
        ax += v0.x + v1.x + v2.x + v3.x;
        ay += v0.y + v1.y + v2.y + v3.y;
        az += v0.z + v1.z + v2.z + v3.z;
        aw += v0.w + v1.w + v2.w + v3.w;
    }
    for (; i < bnd; i += 4) {
        float4 v0 = ef[(size_t)idx[i] * 32 + ch];
        ax += v0.x; ay += v0.y; az += v0.z; aw += v0.w;
    }

    red[t >> 5][ch] = make_float4(ax, ay, az, aw);
    __syncthreads();
    if (t < 64) {
        int ns2 = t >> 5, c2 = t & 31;
        float4 r0 = red[ns2 * 4 + 0][c2];
        float4 r1 = red[ns2 * 4 + 1][c2];
        float4 r2 = red[ns2 * 4 + 2][c2];
        float4 r3 = red[ns2 * 4 + 3][c2];
        int n2 = blockIdx.x * 2 + ns2;
        float sc = invdeg[n2];
        ushort4 o;
        o.x = (unsigned short)f2bf((r0.x + r1.x + r2.x + r3.x) * sc);
        o.y = (unsigned short)f2bf((r0.y + r1.y + r2.y + r3.y) * sc);
        o.z = (unsigned short)f2bf((r0.z + r1.z + r2.z + r3.z) * sc);
        o.w = (unsigned short)f2bf((r0.w + r1.w + r2.w + r3.w) * sc);
        Out[(size_t)n2 * 32 + c2] = o;   // row = 32 x ushort4 = 128 bf16
    }
}

// ---------- relu-gather (bf16 -> bf16): nodeA[n] = invdeg * sum relu(0.5(z[src]+z[n])+b) ----
// 2 nodes x 8 edge-slots x 16 uint4-chunks (8 bf16 each); 4 rows in flight
__global__ __launch_bounds__(256) void relu_gather_k(const uint4* __restrict__ T,
                                                     const int* __restrict__ idx,
                                                     const int* __restrict__ offs,
                                                     const float* __restrict__ bias,
                                                     const float* __restrict__ invdeg,
                                                     uint4* __restrict__ Out) {
    __shared__ float red[16][16][8];
    int t  = threadIdx.x;
    int ns = t >> 7, es = (t >> 4) & 7, ch = t & 15;
    int n  = blockIdx.x * 2 + ns;
    int a = offs[n], bnd = offs[n + 1];

    float zn[8], bb[8], acc[8];
    unpack8(T[(size_t)n * 16 + ch], zn);
#pragma unroll
    for (int j = 0; j < 8; ++j) { bb[j] = bias[ch * 8 + j]; acc[j] = 0.f; }

    int i = a + es;
    for (; i + 24 < bnd; i += 32) {
        int s0 = idx[i], s1 = idx[i + 8], s2 = idx[i + 16], s3 = idx[i + 24];
        uint4 q0 = T[(size_t)s0 * 16 + ch];
        uint4 q1 = T[(size_t)s1 * 16 + ch];
        uint4 q2 = T[(size_t)s2 * 16 + ch];
        uint4 q3 = T[(size_t)s3 * 16 + ch];
        float v[8];
        unpack8(q0, v);
#pragma unroll
        for (int j = 0; j < 8; ++j) acc[j] += fmaxf(0.5f * (v[j] + zn[j]) + bb[j], 0.f);
        unpack8(q1, v);
#pragma unroll
        for (int j = 0; j < 8; ++j) acc[j] += fmaxf(0.5f * (v[j] + zn[j]) + bb[j], 0.f);
        unpack8(q2, v);
#pragma unroll
        for (int j = 0; j < 8; ++j) acc[j] += fmaxf(0.5f * (v[j] + zn[j]) + bb[j], 0.f);
        unpack8(q3, v);
#pragma unroll
        for (int j = 0; j < 8; ++j) acc[j] += fmaxf(0.5f * (v[j] + zn[j]) + bb[j], 0.f);
    }
    for (; i < bnd; i += 8) {
        uint4 q = T[(size_t)idx[i] * 16 + ch];
        float v[8];
        unpack8(q, v);
#pragma unroll
        for (int j = 0; j < 8; ++j) acc[j] += fmaxf(0.5f * (v[j] + zn[j]) + bb[j], 0.f);
    }

#pragma unroll
    for (int j = 0; j < 8; ++j) red[t >> 4][ch][j] = acc[j];
    __syncthreads();
    if (t < 32) {
        int ns2 = t >> 4, c2 = t & 15;
        float s[8];
#pragma unroll
        for (int j = 0; j < 8; ++j) s[j] = 0.f;
#pragma unroll
        for (int sl = 0; sl < 8; ++sl)
#pragma unroll
            for (int j = 0; j < 8; ++j) s[j] += red[ns2 * 8 + sl][c2][j];
        int n2 = blockIdx.x * 2 + ns2;
        float sc = invdeg[n2];
        uint4 o;
        o.x = pack2(s[0] * sc, s[1] * sc);
        o.y = pack2(s[2] * sc, s[3] * sc);
        o.z = pack2(s[4] * sc, s[5] * sc);
        o.w = pack2(s[6] * sc, s[7] * sc);
        Out[(size_t)n2 * 16 + c2] = o;
    }
}

// ---------- sum-gather (bf16) + fused fp32 matvec -> bf16 z ----------
template <int OUT>
__global__ __launch_bounds__(256) void sum_gemm_k(const uint4* __restrict__ T,
                                                  const int* __restrict__ idx,
                                                  const int* __restrict__ offs,
                                                  const float* __restrict__ Wm,
                                                  unsigned short* __restrict__ Z) {
    __shared__ float red[16][16][8];
    __shared__ float xs[2][128];
    int t  = threadIdx.x;
    int ns = t >> 7, es = (t >> 4) & 7, ch = t & 15;
    int n  = blockIdx.x * 2 + ns;
    int a = offs[n], bnd = offs[n + 1];

    float acc[8];
#pragma unroll
    for (int j = 0; j < 8; ++j) acc[j] = 0.f;

    int i = a + es;
    for (; i + 24 < bnd; i += 32) {
        int s0 = idx[i], s1 = idx[i + 8], s2 = idx[i + 16], s3 = idx[i + 24];
        uint4 q0 = T[(size_t)s0 * 16 + ch];
        uint4 q1 = T[(size_t)s1 * 16 + ch];
        uint4 q2 = T[(size_t)s2 * 16 + ch];
        uint4 q3 = T[(size_t)s3 * 16 + ch];
        float v[8];
        unpack8(q0, v);
#pragma unroll
        for (int j = 0; j < 8; ++j) acc[j] += v[j];
        unpack8(q1, v);
#pragma unroll
        for (int j = 0; j < 8; ++j) acc[j] += v[j];
        unpack8(q2, v);
#pragma unroll
        for (int j = 0; j < 8; ++j) acc[j] += v[j];
        unpack8(q3, v);
#pragma unroll
        for (int j = 0; j < 8; ++j) acc[j] += v[j];
    }
    for (; i < bnd; i += 8) {
        uint4 q = T[(size_t)idx[i] * 16 + ch];
        float v[8];
        unpack8(q, v);
#pragma unroll
        for (int j = 0; j < 8; ++j) acc[j] += v[j];
    }

#pragma unroll
    for (int j = 0; j < 8; ++j) red[t >> 4][ch][j] = acc[j];
    __syncthreads();
    if (t < 32) {
        int ns2 = t >> 4, c2 = t & 15;
        float s[8];
#pragma unroll
        for (int j = 0; j < 8; ++j) s[j] = 0.f;
#pragma unroll
        for (int sl = 0; sl < 8; ++sl)
#pragma unroll
            for (int j = 0; j < 8; ++j) s[j] += red[ns2 * 8 + sl][c2][j];
#pragma unroll
        for (int j = 0; j < 8; ++j) xs[ns2][c2 * 8 + j] = s[j];
    }
    __syncthreads();

    // matvec (round-6 proven shape): threads 0..OUT-1, 2 nodes per thread
    if (t < OUT) {
        const float4* wrow = reinterpret_cast<const float4*>(&Wm[(size_t)t * 128]);
        float acc0 = 0.f, acc1 = 0.f;
#pragma unroll 8
        for (int k4 = 0; k4 < 32; ++k4) {
            float4 w  = wrow[k4];
            float4 x0 = *reinterpret_cast<const float4*>(&xs[0][k4 * 4]);
            float4 x1 = *reinterpret_cast<const float4*>(&xs[1][k4 * 4]);
            acc0 += w.x * x0.x + w.y * x0.y + w.z * x0.z + w.w * x0.w;
            acc1 += w.x * x1.x + w.y * x1.y + w.z * x1.z + w.w * x1.w;
        }
        Z[(size_t)(blockIdx.x * 2 + 0) * OUT + t] = (unsigned short)f2bf(acc0);
        Z[(size_t)(blockIdx.x * 2 + 1) * OUT + t] = (unsigned short)f2bf(acc1);
    }
}

// ---------- final edge output: out[e] = 0.5*(z5[src]+z5[dst]) + b5 (64 feats, fp32 out) ----
__global__ __launch_bounds__(256) void edge_out(const uint4* __restrict__ z5,
                                                const float* __restrict__ b5,
                                                const int* __restrict__ src,
                                                const int* __restrict__ dst,
                                                float4* __restrict__ outp) {
    int t = blockIdx.x * 256 + threadIdx.x;
    int e = t >> 3, ch = t & 7;
    if (e < NE) {
        float va[8], vb[8];
        unpack8(z5[(size_t)src[e] * 8 + ch], va);
        unpack8(z5[(size_t)dst[e] * 8 + ch], vb);
        float4 r0, r1;
        r0.x = 0.5f * (va[0] + vb[0]) + b5[ch * 8 + 0];
        r0.y = 0.5f * (va[1] + vb[1]) + b5[ch * 8 + 1];
        r0.z = 0.5f * (va[2] + vb[2]) + b5[ch * 8 + 2];
        r0.w = 0.5f * (va[3] + vb[3]) + b5[ch * 8 + 3];
        r1.x = 0.5f * (va[4] + vb[4]) + b5[ch * 8 + 4];
        r1.y = 0.5f * (va[5] + vb[5]) + b5[ch * 8 + 5];
        r1.z = 0.5f * (va[6] + vb[6]) + b5[ch * 8 + 6];
        r1.w = 0.5f * (va[7] + vb[7]) + b5[ch * 8 + 7];
        outp[(size_t)e * 16 + ch * 2 + 0] = r0;
        outp[(size_t)e * 16 + ch * 2 + 1] = r1;
    }
}

extern "C" void kernel_launch(void* const* d_in, const int* in_sizes, int n_in,
                              void* d_out, int out_size, void* d_ws, size_t ws_size,
                              hipStream_t stream) {
    const float* ef  = (const float*)d_in[0];
    const int*   src = (const int*)d_in[1];
    const int*   dst = (const int*)d_in[2];
    const float* W1 = (const float*)d_in[3];  const float* b1 = (const float*)d_in[4];
    const float* W2 = (const float*)d_in[5];  const float* b2 = (const float*)d_in[6];
    const float* W3 = (const float*)d_in[7];  const float* b3 = (const float*)d_in[8];
    const float* W4 = (const float*)d_in[9];  const float* b4 = (const float*)d_in[10];
    const float* W5 = (const float*)d_in[11]; const float* b5 = (const float*)d_in[12];
    float* out = (float*)d_out;

    char* p = (char*)d_ws;
    auto alloc = [&](size_t bytes) {
        char* r = p;
        p += (bytes + 255) & ~(size_t)255;
        return r;
    };
    int*   deg    = (int*)alloc(NN * 4);
    int*   offs   = (int*)alloc((NN + 1) * 4);
    int*   cursor = (int*)alloc(NN * 4);
    int*   csr    = (int*)alloc((size_t)NE * 4);
    int*   csrc   = (int*)alloc((size_t)NE * 4);
    float* invdeg = (float*)alloc(NN * 4);
    unsigned short* nodeA = (unsigned short*)alloc((size_t)NN * F * 2);  // bf16
    unsigned short* z     = (unsigned short*)alloc((size_t)NN * F * 2);  // bf16

    // CSR build
    hipMemsetAsync(deg, 0, NN * 4, stream);
    count_kernel<<<(NE + 255) / 256, 256, 0, stream>>>(dst, deg);
    scan_kernel<<<1, 1024, 0, stream>>>(deg, offs, cursor, invdeg);
    fill_kernel<<<(NE + 255) / 256, 256, 0, stream>>>(dst, src, cursor, csr, csrc);

    const int GG = NN / 2;                 // 5000 blocks, 2 nodes each
    const uint4* nodeA4 = (const uint4*)nodeA;
    const uint4* z4     = (const uint4*)z;

    // ---- layer 1 ----
    seg_mean_k<<<GG, BLK, 0, stream>>>((const float4*)ef, csr, offs, invdeg, (ushort4*)nodeA);
    sum_gemm_k<128><<<GG, BLK, 0, stream>>>(nodeA4, csrc, offs, W1, z);

    // ---- layers 2..4 (prev layer's edge compute fused into the relu gather) ----
    const float* Wl[3] = {W2, W3, W4};
    const float* bl[3] = {b1, b2, b3};
    for (int L = 0; L < 3; ++L) {
        relu_gather_k<<<GG, BLK, 0, stream>>>(z4, csrc, offs, bl[L], invdeg, (uint4*)nodeA);
        sum_gemm_k<128><<<GG, BLK, 0, stream>>>(nodeA4, csrc, offs, Wl[L], z);
    }

    // ---- layer 5 ----
    relu_gather_k<<<GG, BLK, 0, stream>>>(z4, csrc, offs, b4, invdeg, (uint4*)nodeA);
    sum_gemm_k<64><<<GG, BLK, 0, stream>>>(nodeA4, csrc, offs, W5, z);

    // ---- final per-edge output (82 MB write) ----
    edge_out<<<(NE * 8 + 255) / 256, BLK, 0, stream>>>(z4, b5, src, dst, (float4*)out);
}